// Round 6
// baseline (12681.355 us; speedup 1.0000x reference)
//
#include <hip/hip_runtime.h>

// ============================================================================
// Fully block-local, WEIGHTS-IN-REGISTERS attention-LSTM encoder.
// B=512, T-1=99, N=128, H=256. f32 global I/O, f16 pairs internal (R9 path).
//
// R11: R9/R10 post-mortem: the per-step weight stream (900KB/CU/step) is
// outstanding-load-latency bound at ~61 GB/s/CU (Little's law: ~40 in-flight
// 16B loads x 16B / ~200cy L2 latency) -> 14.7 us/step floor == R9 measured.
// MFMA (R10) didn't touch the stream and regressed by removing the VALU
// work that pipelined with it.
// Fix: keep weights STATIONARY IN REGISTERS. Per-CU regfile = 2MB; full
// weight set = 901KB. 1024-thread block (16 waves, 4/SIMD, VGPR cap 512):
//   - thread j owns gate row j of [Wih|Whh] as 192 f16-pair regs
//   - threads t<792 own a 32-pair W1 slice (s=t>>3, q=t&7)
//   - x-vectors (w|h|c) read from LDS as broadcast u4 (free, same-addr)
//   - all weight loops FULLY UNROLLED (static reg indices, no scratch)
// Per-step weight traffic: ZERO. Phases per step (6 barriers):
//   P1 gates-h-part + z1 partials -> P2 z1 reduce -> P3 E(tanh) ->
//   P4 softmax+w -> P5 gates-w-part + gl -> P6 LSTM + h,c repack.
// Numerics identical to R9 (f16 pairs, fdot2, f32 accum): absmax 4.88e-4.
// 256 blocks x 1024 threads, 1 block/CU, LDS ~125KB.
// ============================================================================

typedef unsigned int  uint32;
typedef unsigned short u16;
typedef _Float16 h2  __attribute__((ext_vector_type(2)));
typedef uint32   u4  __attribute__((ext_vector_type(4)));

#define TS 99
#define BB 512
#define NN 128
#define HH 256

__device__ __forceinline__ float frcp(float x){ return __builtin_amdgcn_rcpf(x); }
__device__ __forceinline__ float ftanh(float x){
  float t = __expf(2.f * x);
  return 1.f - 2.f * frcp(t + 1.f);
}
__device__ __forceinline__ float fsig(float x){
  return frcp(1.f + __expf(-x));
}
__device__ __forceinline__ uint32 pk2(float a, float b){
  union { h2 h; uint32 u; } v;
  v.h[0] = (_Float16)a; v.h[1] = (_Float16)b; return v.u;
}
__device__ __forceinline__ u16 f2h(float f){
  union { _Float16 h; u16 u; } v; v.h = (_Float16)f; return v.u;
}
__device__ __forceinline__ float h2ff(u16 u){
  union { u16 u2; _Float16 h; } v; v.u2 = u; return (float)v.h;
}
__device__ __forceinline__ float dot2(uint32 a, uint32 b, float c){
  union { uint32 u; h2 h; } x, y; x.u = a; y.u = b;
#if __has_builtin(__builtin_amdgcn_fdot2)
  return __builtin_amdgcn_fdot2(x.h, y.h, c, false);
#else
  c = fmaf((float)x.h[0], (float)y.h[0], c);
  return fmaf((float)x.h[1], (float)y.h[1], c);
#endif
}

struct KParams {
  const float *in, *W1, *b1, *W2, *b2, *W3, *Wih, *Whh, *bih, *bhh;
  float *out;           // [weighted B*99*128 | encoded B*99*256] f32
  const uint32 *Wgt;    // [192 pair][1024 j] f16-pairs, row j = [Wih|Whh]
  const uint32 *W1t;    // [256 pair][112 s]  f16-pairs, k over [h|c]
};

// ---- pack weights to f16 pairs, pair-major (coalesced reg loads) ----
__global__ void pack_kernel(const float* W1, const float* Wih, const float* Whh,
                            uint32* Wgt, uint32* W1t)
{
  int idx = blockIdx.x * 256 + threadIdx.x;
  if (idx < 192 * 1024) {
    int pp = idx >> 10, j = idx & 1023;
    float a, b;
    if (pp < 64) { a = Wih[(size_t)j * 128 + 2 * pp];
                   b = Wih[(size_t)j * 128 + 2 * pp + 1]; }
    else { int q = pp - 64; a = Whh[(size_t)j * 256 + 2 * q];
                            b = Whh[(size_t)j * 256 + 2 * q + 1]; }
    Wgt[idx] = pk2(a, b);
  } else {
    int v = idx - 192 * 1024;
    if (v < 256 * 112) {
      int pp = v / 112, s = v % 112;
      uint32 r = 0;
      if (s < TS) r = pk2(W1[(size_t)s * 512 + 2 * pp],
                          W1[(size_t)s * 512 + 2 * pp + 1]);
      W1t[v] = r;
    }
  }
}

__global__ __launch_bounds__(1024, 4) void enc_kernel(KParams p)
{
  // stride 102 (odd dword count) -> bank spread for per-row u16 reads
  __shared__ u16    int_s[2][128][102];  // f16 in[b][n][t]
  __shared__ u16    z2s[2][128][102];    // f16 z2[b][n][s] (+b2)
  __shared__ uint32 hcp[2][256];         // f16 pairs: h pairs 0..127 | c 128..255
  __shared__ uint32 wp[2][64];           // f16 pairs: w n-pairs
  __shared__ float  z1part[2][8][112];
  __shared__ float  z1s[2][112];
  __shared__ float  epart[2][4][128];
  __shared__ float  gl[2][1024];
  __shared__ float  w3s[128], b1s[128];

  const int tid = threadIdx.x;
  const int blk = blockIdx.x;
  const int b0  = blk * 2;               // this block's two batches

  float* outw = p.out;
  float* oute = p.out + (size_t)BB * TS * NN;

  // ---------------- prologue ----------------
  for (int b = 0; b < 2; ++b) {          // stage inputs f16, column layout
    const float* src = p.in + (size_t)(b0 + b) * TS * NN;
    for (int idx = tid; idx < TS * NN; idx += 1024) {
      int t = idx >> 7, n = idx & 127;
      int_s[b][n][t] = f2h(src[idx]);
    }
  }
  if (tid < 128) {
    w3s[tid] = (tid < TS) ? p.W3[tid] : 0.f;
    b1s[tid] = (tid < TS) ? p.b1[tid] : 0.f;
  }
  if (tid < 512) hcp[tid >> 8][tid & 255] = 0;   // h = c = 0 at t=0
  __syncthreads();
  {  // z2[b][n][s] = b2[s] + sum_t in[b][t][n] * W2[s][t]
    int n = tid & 127, b = (tid >> 7) & 1, hf = tid >> 8;
    int s0 = hf * 25, s1 = (hf == 3) ? TS : s0 + 25;
    const u16* ir = int_s[b][n];
    for (int s = s0; s < s1; ++s) {
      float acc = p.b2[s];
      const float* w2r = p.W2 + s * TS;
      for (int tt = 0; tt + 1 < TS; tt += 2) {
        uint32 pr = *(const uint32*)&ir[tt];
        acc = fmaf(h2ff((u16)(pr & 0xFFFFu)), w2r[tt],     acc);
        acc = fmaf(h2ff((u16)(pr >> 16)),     w2r[tt + 1], acc);
      }
      acc = fmaf(h2ff(ir[98]), w2r[98], acc);
      z2s[b][n][s] = f2h(acc);
    }
  }

  // ---- load weights into registers (fully unrolled, static indices) ----
  uint32 wg[192];                        // gate row j = tid: [Wih|Whh] pairs
  #pragma unroll
  for (int i = 0; i < 192; ++i) wg[i] = p.Wgt[(size_t)i * 1024 + tid];
  const float br = p.bih[tid] + p.bhh[tid];
  const int zs_s = tid >> 3, zs_q = tid & 7;     // W1 slice owner (tid<792)
  uint32 w1r[32];
  #pragma unroll
  for (int i = 0; i < 32; ++i)
    w1r[i] = (tid < 792) ? p.W1t[(size_t)(zs_q * 32 + i) * 112 + zs_s] : 0u;
  __syncthreads();

  float creg = 0.f;                      // c for (lb, lu), f32 forever
  const int lu = tid & 255, lb = (tid >> 8) & 1;

  for (int t = 0; t < TS; ++t) {
    // prefetch x_t for softmax (lands by P4)
    float x0v = 0.f, x1v = 0.f;
    if (tid < 128) {
      int b = tid >> 6, ln = tid & 63;
      const float* xr = p.in + ((size_t)(b0 + b) * TS + t) * NN;
      x0v = xr[ln]; x1v = xr[ln + 64];
    }

    // ===== P1: gates h-part (reg weights) + z1 partials ====================
    float ga0 = 0.f, ga1 = 0.f;
    #pragma unroll
    for (int kb = 16; kb < 48; ++kb) {   // h pairs (kb-16)*4 .. +4
      u4 x0 = *(const u4*)&hcp[0][(kb - 16) * 4];
      u4 x1 = *(const u4*)&hcp[1][(kb - 16) * 4];
      #pragma unroll
      for (int i = 0; i < 4; ++i) {
        ga0 = dot2(wg[kb * 4 + i], x0[i], ga0);
        ga1 = dot2(wg[kb * 4 + i], x1[i], ga1);
      }
    }
    if (tid < 792) {
      float za0 = 0.f, za1 = 0.f;
      #pragma unroll
      for (int ib = 0; ib < 8; ++ib) {
        u4 x0 = *(const u4*)&hcp[0][zs_q * 32 + ib * 4];
        u4 x1 = *(const u4*)&hcp[1][zs_q * 32 + ib * 4];
        #pragma unroll
        for (int i = 0; i < 4; ++i) {
          za0 = dot2(w1r[ib * 4 + i], x0[i], za0);
          za1 = dot2(w1r[ib * 4 + i], x1[i], za1);
        }
      }
      z1part[0][zs_q][zs_s] = za0;
      z1part[1][zs_q][zs_s] = za1;
    }
    __syncthreads();

    // ===== P2: z1 reduce ===================================================
    if (tid < 256) {
      int b = tid >> 7, s = tid & 127;
      if (s < TS) {
        float v = b1s[s];
        #pragma unroll
        for (int q = 0; q < 8; ++q) v += z1part[b][q][s];
        z1s[b][s] = v;
      }
    }
    __syncthreads();

    // ===== P3: E: e[b][n] = sum_s w3[s] * tanh(z1[b][s] + z2[b][n][s]) =====
    {
      int n = tid & 127, b = (tid >> 7) & 1, hf = tid >> 8;
      int s0 = hf * 25, s1 = (hf == 3) ? TS : s0 + 25;
      const u16* zr = z2s[b][n];
      float acce = 0.f;
      for (int s = s0; s < s1; ++s)
        acce = fmaf(w3s[s], ftanh(z1s[b][s] + h2ff(zr[s])), acce);
      epart[b][hf][n] = acce;
    }
    __syncthreads();

    // ===== P4: softmax + w = attn * x_t (waves 0-1) ========================
    if (tid < 128) {
      int b = tid >> 6, ln = tid & 63;
      float v0 = (epart[b][0][ln]      + epart[b][1][ln])
               + (epart[b][2][ln]      + epart[b][3][ln]);
      float v1 = (epart[b][0][ln + 64] + epart[b][1][ln + 64])
               + (epart[b][2][ln + 64] + epart[b][3][ln + 64]);
      float m = fmaxf(v0, v1);
      for (int off = 32; off; off >>= 1) m = fmaxf(m, __shfl_xor(m, off));
      float e0 = __expf(v0 - m), e1 = __expf(v1 - m);
      float sm = e0 + e1;
      for (int off = 32; off; off >>= 1) sm += __shfl_xor(sm, off);
      float r = frcp(sm);
      float w0 = e0 * r * x0v;
      float w1 = e1 * r * x1v;
      float* orow = outw + ((size_t)(b0 + b) * TS + t) * NN;
      orow[ln]      = w0;                // f32 output
      orow[ln + 64] = w1;
      float w0n = __shfl_xor(w0, 1), w1n = __shfl_xor(w1, 1);
      if ((ln & 1) == 0) {               // pack adjacent-n pairs as f16x2
        wp[b][ln >> 1]        = pk2(w0, w0n);
        wp[b][32 + (ln >> 1)] = pk2(w1, w1n);
      }
    }
    __syncthreads();

    // ===== P5: gates w-part (reg weights) + gl write =======================
    #pragma unroll
    for (int kb = 0; kb < 16; ++kb) {    // w pairs kb*4 .. +4
      u4 x0 = *(const u4*)&wp[0][kb * 4];
      u4 x1 = *(const u4*)&wp[1][kb * 4];
      #pragma unroll
      for (int i = 0; i < 4; ++i) {
        ga0 = dot2(wg[kb * 4 + i], x0[i], ga0);
        ga1 = dot2(wg[kb * 4 + i], x1[i], ga1);
      }
    }
    gl[0][tid] = ga0 + br;
    gl[1][tid] = ga1 + br;
    __syncthreads();

    // ===== P6: LSTM pointwise (waves 0-7) + h,c repack =====================
    if (tid < 512) {
      float iv = gl[lb][lu],       fv = gl[lb][256 + lu];
      float gv = gl[lb][512 + lu], ov = gl[lb][768 + lu];
      float cn = fsig(fv) * creg + fsig(iv) * ftanh(gv);
      float hn = fsig(ov) * ftanh(cn);
      creg = cn;
      oute[((size_t)(b0 + lb) * TS + t) * HH + lu] = hn;   // f32 output
      float hx = __shfl_xor(hn, 1);      // lu parity == lane parity
      float cx = __shfl_xor(cn, 1);
      if ((lu & 1) == 0) {
        hcp[lb][lu >> 1]         = pk2(hn, hx);
        hcp[lb][128 + (lu >> 1)] = pk2(cn, cx);
      }
    }
    __syncthreads();
  }
}

extern "C" void kernel_launch(void* const* d_in, const int* in_sizes, int n_in,
                              void* d_out, int out_size, void* d_ws, size_t ws_size,
                              hipStream_t stream)
{
  KParams p;
  p.in  = (const float*)d_in[0];
  p.W1  = (const float*)d_in[1];
  p.b1  = (const float*)d_in[2];
  p.W2  = (const float*)d_in[3];
  p.b2  = (const float*)d_in[4];
  p.W3  = (const float*)d_in[5];
  // d_in[6] = b3: softmax shift-invariant, unused
  p.Wih = (const float*)d_in[7];
  p.Whh = (const float*)d_in[8];
  p.bih = (const float*)d_in[9];
  p.bhh = (const float*)d_in[10];
  p.out = (float*)d_out;

  char* ws = (char*)d_ws;
  const size_t wgtBytes = 192ull * 1024 * 4;      // 786,432
  const size_t w1tBytes = 256ull * 112 * 4;       // 114,688
  const size_t needBytes = wgtBytes + w1tBytes;   // 901,120
  if (ws_size < needBytes) return;  // fail loudly (poisoned output)

  uint32* Wgt = (uint32*)ws;
  uint32* W1t = (uint32*)(ws + wgtBytes);
  p.Wgt = Wgt;
  p.W1t = W1t;

  // pack weights (writes fully cover both buffers; same-stream ordering
  // guarantees visibility to enc_kernel). No memset needed: no flags, and
  // every workspace byte is pack-written before enc_kernel reads it.
  const int packElems = 192 * 1024 + 256 * 112;   // 225,280
  pack_kernel<<<dim3((packElems + 255) / 256), dim3(256), 0, stream>>>(
      p.W1, p.Wih, p.Whh, Wgt, W1t);

  enc_kernel<<<dim3(256), dim3(1024), 0, stream>>>(p);
}

// Round 7
// 9009.054 us; speedup vs baseline: 1.4076x; 1.4076x over previous
//
#include <hip/hip_runtime.h>

// ============================================================================
// Fully block-local attention-LSTM encoder. B=512, T-1=99, N=128, H=256.
//
// R12 = R9 (proven 1412us, stream-bound) + stream reduction + deeper pipeline.
// R11 lesson: CU regfile = 512KB (2048 VGPR x 64 lane x 4B), NOT 2MB; full
// parking impossible; 1024-thr blocks cap VGPR at 128 -> R11 spilled 21GB.
// R12, within measured budgets:
//  - 512 thr, launch_bounds(512,2) -> 256 VGPR cap (8 waves = full pool)
//  - reg-park w-part of both owned gate rows: wg_w[128] = 256KB/CU off stream
//  - LDS-park h-pairs 0..11 (49KB) in int_s, which is dead after z2 prologue
//  - stream remainder (h-pairs 12..127 = 475KB + W1 131KB = 606KB/step) with
//    8-load double-buffered groups (2x R9 in-flight depth)
//  - weights replicated x2; alternating blocks per XCD use different copies
//    (spreads same-line L2-slice contention)
//  - empty asm on stream base pointers each step blocks LICM (no R11-style
//    hoist-then-spill of loop-invariant weight loads)
//  - h-gates stream shares one barrier region with E-phase tanh: 2 waves/SIMD
//    co-schedule -> tanh hides L2 latency (m114 overlap)
// Phase order/accumulation identical to R9 -> absmax expected 4.88e-4.
// 256 blocks x 512 threads, 1 block/CU, LDS 127.5KB. No flags, no sc1.
// ============================================================================

typedef unsigned int  uint32;
typedef unsigned short u16;
typedef _Float16 h2  __attribute__((ext_vector_type(2)));
typedef uint32   u4  __attribute__((ext_vector_type(4)));

#define TS 99
#define BB 512
#define NN 128
#define HH 256

__device__ __forceinline__ float frcp(float x){ return __builtin_amdgcn_rcpf(x); }
__device__ __forceinline__ float ftanh(float x){
  float t = __expf(2.f * x);
  return 1.f - 2.f * frcp(t + 1.f);
}
__device__ __forceinline__ float fsig(float x){
  return frcp(1.f + __expf(-x));
}
__device__ __forceinline__ uint32 pk2(float a, float b){
  union { h2 h; uint32 u; } v;
  v.h[0] = (_Float16)a; v.h[1] = (_Float16)b; return v.u;
}
__device__ __forceinline__ u16 f2h(float f){
  union { _Float16 h; u16 u; } v; v.h = (_Float16)f; return v.u;
}
__device__ __forceinline__ float h2ff(u16 u){
  union { u16 u2; _Float16 h; } v; v.u2 = u; return (float)v.h;
}
__device__ __forceinline__ float dot2(uint32 a, uint32 b, float c){
  union { uint32 u; h2 h; } x, y; x.u = a; y.u = b;
#if __has_builtin(__builtin_amdgcn_fdot2)
  return __builtin_amdgcn_fdot2(x.h, y.h, c, false);
#else
  c = fmaf((float)x.h[0], (float)y.h[0], c);
  return fmaf((float)x.h[1], (float)y.h[1], c);
#endif
}

struct KParams {
  const float *in, *W1, *b1, *W2, *b2, *W3, *Wih, *Whh, *bih, *bhh;
  float *out;          // [weighted B*99*128 | encoded B*99*256] f32
  const uint32 *Wgw;   // [64 p][1024 j]            w-part (reg-parked)
  const uint32 *Whp;   // [2 c][32 kb][1024 j][4 i] h-part (stream + LDS park)
  const uint32 *W1c;   // [2 c][64 kpb][128 s][4 i] W1 (stream)
};

// ---- pack weights to f16 pairs (runs once per launch; ~1.5MB, trivial) ----
__global__ void pack_kernel(const float* W1, const float* Wih, const float* Whh,
                            uint32* Wgw, uint32* Whp, uint32* W1c)
{
  int idx = blockIdx.x * 256 + threadIdx.x;
  if (idx < 64 * 1024) {                       // Wgw[p][j]
    int p = idx >> 10, j = idx & 1023;
    Wgw[idx] = pk2(Wih[(size_t)j * 128 + 2 * p],
                   Wih[(size_t)j * 128 + 2 * p + 1]);
  } else if (idx < 64 * 1024 + 2 * 32 * 1024 * 4) {
    int v = idx - 64 * 1024;                   // Whp[c][kb][j][i]
    int i = v & 3, j = (v >> 2) & 1023, kb = (v >> 12) & 31;
    int ph = kb * 4 + i;                       // h-pair 0..127
    Whp[v] = pk2(Whh[(size_t)j * 256 + 2 * ph],
                 Whh[(size_t)j * 256 + 2 * ph + 1]);
  } else {
    int w = idx - (64 * 1024 + 2 * 32 * 1024 * 4);
    if (w < 2 * 64 * 128 * 4) {                // W1c[c][kpb][s][i]
      int i = w & 3, s = (w >> 2) & 127, kpb = (w >> 9) & 63;
      int kp = kpb * 4 + i;                    // k-pair over [h(128)|c(128)]
      uint32 r = 0;
      if (s < TS) r = pk2(W1[(size_t)s * 512 + 2 * kp],
                          W1[(size_t)s * 512 + 2 * kp + 1]);
      W1c[w] = r;
    }
  }
}

// consume one h/w kb: 2 weight u4 (rows tid, tid+512) x 2 batch broadcasts
#define GCONS1(XB, W0, W1R, kb) do {                                   \
    u4 x0_ = *(const u4*)&XB[0][(kb) * 4];                             \
    u4 x1_ = *(const u4*)&XB[1][(kb) * 4];                             \
    _Pragma("unroll")                                                  \
    for (int ii_ = 0; ii_ < 4; ++ii_) {                                \
      a00 = dot2(W0[ii_], x0_[ii_], a00);                              \
      a01 = dot2(W1R[ii_], x0_[ii_], a01);                             \
      a10 = dot2(W0[ii_], x1_[ii_], a10);                              \
      a11 = dot2(W1R[ii_], x1_[ii_], a11);                             \
    } } while (0)

#define GCONS4(P0,P1,P2,P3,P4,P5,P6,P7, kb) do {                       \
    GCONS1(hcp, P0, P1, (kb));     GCONS1(hcp, P2, P3, (kb) + 1);      \
    GCONS1(hcp, P4, P5, (kb) + 2); GCONS1(hcp, P6, P7, (kb) + 3); } while (0)

#define LOADG(P0,P1,P2,P3,P4,P5,P6,P7, kb) do {                        \
    P0 = wh4[(kb) * 1024 + tid];       P1 = wh4[(kb) * 1024 + tid + 512];     \
    P2 = wh4[((kb)+1) * 1024 + tid];   P3 = wh4[((kb)+1) * 1024 + tid + 512]; \
    P4 = wh4[((kb)+2) * 1024 + tid];   P5 = wh4[((kb)+2) * 1024 + tid + 512]; \
    P6 = wh4[((kb)+3) * 1024 + tid];   P7 = wh4[((kb)+3) * 1024 + tid + 512]; \
  } while (0)

__global__ __launch_bounds__(512, 2) void enc_kernel(KParams p)
{
  // scratch: in[b][n][t] during prologue, then h-park (kbs 0..2, 48KB)
  __shared__ __align__(16) u16    scratch[2][128][102];
  __shared__ __align__(16) u16    z2s[2][128][102];   // f16 z2[b][n][s] (+b2)
  __shared__ __align__(16) uint32 hcp[2][256];        // f16 pairs: h|c
  __shared__ __align__(16) uint32 wp[2][64];          // f16 pairs: w[n]
  __shared__ __align__(16) float  z1part[2][4][128];
  __shared__ __align__(16) float  z1s[2][128];
  __shared__ float  epart[2][2][128];
  __shared__ float  gl[2][1024];
  __shared__ float  biasl[1024];
  __shared__ float  w3s[128], b1s[128];

  const int tid = threadIdx.x;
  const int blk = blockIdx.x;
  const int b0  = blk * 2;               // this block's two batches
  const int wc  = (blk >> 3) & 1;        // weight copy (alternates per XCD)

  float* outw = p.out;
  float* oute = p.out + (size_t)BB * TS * NN;

  // ---------------- prologue ----------------
  for (int b = 0; b < 2; ++b) {          // stage inputs f16, column layout
    const float* src = p.in + (size_t)(b0 + b) * TS * NN;
    for (int idx = tid; idx < TS * NN; idx += 512) {
      int t = idx >> 7, n = idx & 127;
      scratch[b][n][t] = f2h(src[idx]);
    }
  }
  if (tid < 128) {
    w3s[tid] = (tid < TS) ? p.W3[tid] : 0.f;
    b1s[tid] = (tid < TS) ? p.b1[tid] : 0.f;
  }
  hcp[tid >> 8][tid & 255] = 0;          // h = c = 0 at t=0  (512 covers all)
  biasl[tid]       = p.bih[tid]       + p.bhh[tid];
  biasl[tid + 512] = p.bih[tid + 512] + p.bhh[tid + 512];
  __syncthreads();
  {  // z2[b][n][s] = b2[s] + sum_t in[b][t][n] * W2[s][t]
    int n = tid & 127, b = (tid >> 7) & 1, hf = tid >> 8;
    int s0 = hf * 50, s1 = hf ? TS : 50;
    const u16* ir = scratch[b][n];
    for (int s = s0; s < s1; ++s) {
      float acc = p.b2[s];
      const float* w2r = p.W2 + s * TS;
      for (int tt = 0; tt + 1 < TS; tt += 2) {
        uint32 pr = *(const uint32*)&ir[tt];
        acc = fmaf(h2ff((u16)(pr & 0xFFFFu)), w2r[tt],     acc);
        acc = fmaf(h2ff((u16)(pr >> 16)),     w2r[tt + 1], acc);
      }
      acc = fmaf(h2ff(ir[98]), w2r[98], acc);
      z2s[b][n][s] = f2h(acc);
    }
  }
  __syncthreads();

  // ---- reg-park w-part (128 VGPR) + LDS-park h kbs 0..2 into scratch ----
  uint32 wg_w[128];
  #pragma unroll
  for (int i = 0; i < 64; ++i) wg_w[i] = p.Wgw[(size_t)i * 1024 + tid];
  #pragma unroll
  for (int i = 0; i < 64; ++i) wg_w[64 + i] = p.Wgw[(size_t)i * 1024 + tid + 512];

  u4* hp4 = (u4*)&scratch[0][0][0];      // [3 kb][1024 j] u4 = 48KB
  {
    const u4* src = (const u4*)p.Whp + (size_t)wc * 32768;
    #pragma unroll
    for (int r = 0; r < 6; ++r) hp4[r * 512 + tid] = src[r * 512 + tid];
  }
  __syncthreads();

  float creg = 0.f;                      // c for (lb, lu), f32 forever
  const int lu = tid & 255, lb = (tid >> 8) & 1;
  const int s127 = tid & 127, zq = tid >> 7;   // z1 ownership (4 k-quarters)

  const u4* wh4  = (const u4*)p.Whp + (size_t)wc * 32768;   // [32][1024] u4
  const u4* w1c4 = (const u4*)p.W1c + (size_t)wc * 8192;    // [64][128]  u4

  for (int t = 0; t < TS; ++t) {
    // block LICM of loop-invariant weight loads (R11 hoist-then-spill trap)
    asm volatile("" : "+s"(wh4), "+s"(w1c4));

    float a00 = 0.f, a01 = 0.f, a10 = 0.f, a11 = 0.f;  // [batch][row-half]

    // ===== P1: z1 (W1 stream) + parked-h gate contribution =================
    {
      u4 w1b[16];
      #pragma unroll
      for (int i = 0; i < 16; ++i)
        w1b[i] = w1c4[(zq * 16 + i) * 128 + s127];
      #pragma unroll
      for (int kb = 0; kb < 3; ++kb) {   // LDS-parked h kbs (pairs 0..11)
        u4 w0 = hp4[kb * 1024 + tid];
        u4 w1r = hp4[kb * 1024 + tid + 512];
        GCONS1(hcp, w0, w1r, kb);
      }
      float za0 = 0.f, za1 = 0.f;
      #pragma unroll
      for (int i = 0; i < 16; ++i) {
        u4 x0 = *(const u4*)&hcp[0][(zq * 16 + i) * 4];
        u4 x1 = *(const u4*)&hcp[1][(zq * 16 + i) * 4];
        #pragma unroll
        for (int ii = 0; ii < 4; ++ii) {
          za0 = dot2(w1b[i][ii], x0[ii], za0);
          za1 = dot2(w1b[i][ii], x1[ii], za1);
        }
      }
      z1part[0][zq][s127] = za0;
      z1part[1][zq][s127] = za1;
    }
    __syncthreads();

    // ===== P2: z1 reduce ===================================================
    if (tid < 256) {
      int b = tid >> 7, s = tid & 127;
      z1s[b][s] = b1s[s] + ((z1part[b][0][s] + z1part[b][1][s])
                          + (z1part[b][2][s] + z1part[b][3][s]));
    }
    __syncthreads();

    // ===== P3: h-gates stream (kbs 3..31) + E phase, one barrier region ====
    {
      u4 A0,A1,A2,A3,A4,A5,A6,A7, B0,B1,B2,B3,B4,B5,B6,B7;
      LOADG(A0,A1,A2,A3,A4,A5,A6,A7, 3);
      LOADG(B0,B1,B2,B3,B4,B5,B6,B7, 7);
      {  // E: e[b][n] = sum_s w3[s] * tanh(z1[b][s] + z2[b][n][s])
        int n = tid & 127, b = (tid >> 7) & 1, hf = tid >> 8;
        int s0 = hf * 50, s1 = hf ? TS : 50;
        const u16* zr = z2s[b][n];
        float acce = 0.f;
        for (int s = s0; s < s1; ++s)
          acce = fmaf(w3s[s], ftanh(z1s[b][s] + h2ff(zr[s])), acce);
        epart[b][hf][n] = acce;
      }
      GCONS4(A0,A1,A2,A3,A4,A5,A6,A7, 3);
      LOADG(A0,A1,A2,A3,A4,A5,A6,A7, 11);
      GCONS4(B0,B1,B2,B3,B4,B5,B6,B7, 7);
      LOADG(B0,B1,B2,B3,B4,B5,B6,B7, 15);
      GCONS4(A0,A1,A2,A3,A4,A5,A6,A7, 11);
      LOADG(A0,A1,A2,A3,A4,A5,A6,A7, 19);
      GCONS4(B0,B1,B2,B3,B4,B5,B6,B7, 15);
      LOADG(B0,B1,B2,B3,B4,B5,B6,B7, 23);
      GCONS4(A0,A1,A2,A3,A4,A5,A6,A7, 19);
      LOADG(A0,A1,A2,A3,A4,A5,A6,A7, 27);
      GCONS4(B0,B1,B2,B3,B4,B5,B6,B7, 23);
      B0 = wh4[31 * 1024 + tid];
      B1 = wh4[31 * 1024 + tid + 512];
      GCONS4(A0,A1,A2,A3,A4,A5,A6,A7, 27);
      GCONS1(hcp, B0, B1, 31);
    }
    __syncthreads();

    // ===== P4: softmax + w = attn * x_t (waves 0-1) ========================
    if (tid < 128) {
      int b = tid >> 6, ln = tid & 63;
      float v0 = epart[b][0][ln]      + epart[b][1][ln];
      float v1 = epart[b][0][ln + 64] + epart[b][1][ln + 64];
      float m = fmaxf(v0, v1);
      for (int off = 32; off; off >>= 1) m = fmaxf(m, __shfl_xor(m, off));
      float e0 = __expf(v0 - m), e1 = __expf(v1 - m);
      float sm = e0 + e1;
      for (int off = 32; off; off >>= 1) sm += __shfl_xor(sm, off);
      float r = frcp(sm);
      const float* xr = p.in + ((size_t)(b0 + b) * TS + t) * NN;
      float w0 = e0 * r * xr[ln];
      float w1 = e1 * r * xr[ln + 64];
      float* orow = outw + ((size_t)(b0 + b) * TS + t) * NN;
      orow[ln]      = w0;                // f32 output
      orow[ln + 64] = w1;
      float w0n = __shfl_xor(w0, 1), w1n = __shfl_xor(w1, 1);
      if ((ln & 1) == 0) {               // pack adjacent-n pairs as f16x2
        wp[b][ln >> 1]        = pk2(w0, w0n);
        wp[b][32 + (ln >> 1)] = pk2(w1, w1n);
      }
    }
    __syncthreads();

    // ===== P5: w-gates from PARKED regs + gl write =========================
    #pragma unroll
    for (int kb = 0; kb < 16; ++kb) {
      u4 x0 = *(const u4*)&wp[0][kb * 4];
      u4 x1 = *(const u4*)&wp[1][kb * 4];
      #pragma unroll
      for (int i = 0; i < 4; ++i) {
        a00 = dot2(wg_w[kb * 4 + i],      x0[i], a00);
        a01 = dot2(wg_w[64 + kb * 4 + i], x0[i], a01);
        a10 = dot2(wg_w[kb * 4 + i],      x1[i], a10);
        a11 = dot2(wg_w[64 + kb * 4 + i], x1[i], a11);
      }
    }
    gl[0][tid]       = a00 + biasl[tid];
    gl[0][tid + 512] = a01 + biasl[tid + 512];
    gl[1][tid]       = a10 + biasl[tid];
    gl[1][tid + 512] = a11 + biasl[tid + 512];
    __syncthreads();

    // ===== P6: LSTM pointwise + h,c repack =================================
    {
      float iv = gl[lb][lu],       fv = gl[lb][256 + lu];
      float gv = gl[lb][512 + lu], ov = gl[lb][768 + lu];
      float cn = fsig(fv) * creg + fsig(iv) * ftanh(gv);
      float hn = fsig(ov) * ftanh(cn);
      creg = cn;
      oute[((size_t)(b0 + lb) * TS + t) * HH + lu] = hn;   // f32 output
      float hx = __shfl_xor(hn, 1);      // lu parity == lane parity
      float cx = __shfl_xor(cn, 1);
      if ((lu & 1) == 0) {
        hcp[lb][lu >> 1]         = pk2(hn, hx);
        hcp[lb][128 + (lu >> 1)] = pk2(cn, cx);
      }
    }
    __syncthreads();
  }
}

extern "C" void kernel_launch(void* const* d_in, const int* in_sizes, int n_in,
                              void* d_out, int out_size, void* d_ws, size_t ws_size,
                              hipStream_t stream)
{
  KParams p;
  p.in  = (const float*)d_in[0];
  p.W1  = (const float*)d_in[1];
  p.b1  = (const float*)d_in[2];
  p.W2  = (const float*)d_in[3];
  p.b2  = (const float*)d_in[4];
  p.W3  = (const float*)d_in[5];
  // d_in[6] = b3: softmax shift-invariant, unused
  p.Wih = (const float*)d_in[7];
  p.Whh = (const float*)d_in[8];
  p.bih = (const float*)d_in[9];
  p.bhh = (const float*)d_in[10];
  p.out = (float*)d_out;

  char* ws = (char*)d_ws;
  const size_t wgwBytes = 64ull * 1024 * 4;            // 262,144
  const size_t whpBytes = 2ull * 32 * 1024 * 4 * 4;    // 1,048,576
  const size_t w1cBytes = 2ull * 64 * 128 * 4 * 4;     // 262,144
  const size_t needBytes = wgwBytes + whpBytes + w1cBytes;  // 1,572,864
  if (ws_size < needBytes) return;  // fail loudly (poisoned output)

  uint32* Wgw = (uint32*)ws;
  uint32* Whp = (uint32*)(ws + wgwBytes);
  uint32* W1c = (uint32*)(ws + wgwBytes + whpBytes);
  p.Wgw = Wgw;
  p.Whp = Whp;
  p.W1c = W1c;

  // pack weights (fully covers all buffers; same-stream ordering guarantees
  // visibility; no flags -> no memset needed)
  const int packElems = 64 * 1024 + 2 * 32 * 1024 * 4 + 2 * 64 * 128 * 4;
  pack_kernel<<<dim3((packElems + 255) / 256), dim3(256), 0, stream>>>(
      p.W1, p.Wih, p.Whh, Wgw, Whp, W1c);

  enc_kernel<<<dim3(256), dim3(512), 0, stream>>>(p);
}

// Round 8
// 8650.426 us; speedup vs baseline: 1.4660x; 1.0415x over previous
//
#include <hip/hip_runtime.h>

// ============================================================================
// Fully block-local attention-LSTM encoder. B=512, T-1=99, N=128, H=256.
//
// R13 == R12 with the launch-bounds bug fixed. R11/R12 post-mortem: hipcc
// treats __launch_bounds__'s 2nd arg as CUDA min-BLOCKS-per-CU:
//   R11 (1024,4) -> 8 waves/SIMD -> 64 VGPR cap (measured 64, spilled 21GB)
//   R12 (512,2)  -> 4 waves/SIMD -> 128 VGPR cap (measured 128, spilled 24GB)
// (512,1) -> 2 waves/SIMD -> 256 VGPR cap. Peak live ~220 regs -> no spill.
// 1 block/CU was already forced by 127.5KB LDS, so occupancy is unchanged.
//
// Design (R12): R9 (proven 1412us, stream-bound) + stream reduction:
//  - reg-park w-part of both owned gate rows: wg_w[128] = 256KB/CU off stream
//    (also removes w-part LDS broadcasts: ds_read_b128 ~12cy each, ~5us/step
//    of LDS pipe at R9's 128 reads/thread/step)
//  - LDS-park h-pairs 0..11 (48KB) in int_s, dead after z2 prologue
//  - stream remainder (h-pairs 12..127 = 475KB + W1 131KB = 606KB/step) with
//    8-load double-buffered groups
//  - weights replicated x2; alternating block groups use different copies
//  - empty asm on stream base pointers blocks LICM (hoist-then-spill trap)
//  - h-gates stream shares one barrier region with E-phase tanh (m114 overlap)
// Phase order/accumulation identical to R9 -> absmax expected 4.88e-4.
// 256 blocks x 512 threads, 1 block/CU. No flags, no sc1.
// ============================================================================

typedef unsigned int  uint32;
typedef unsigned short u16;
typedef _Float16 h2  __attribute__((ext_vector_type(2)));
typedef uint32   u4  __attribute__((ext_vector_type(4)));

#define TS 99
#define BB 512
#define NN 128
#define HH 256

__device__ __forceinline__ float frcp(float x){ return __builtin_amdgcn_rcpf(x); }
__device__ __forceinline__ float ftanh(float x){
  float t = __expf(2.f * x);
  return 1.f - 2.f * frcp(t + 1.f);
}
__device__ __forceinline__ float fsig(float x){
  return frcp(1.f + __expf(-x));
}
__device__ __forceinline__ uint32 pk2(float a, float b){
  union { h2 h; uint32 u; } v;
  v.h[0] = (_Float16)a; v.h[1] = (_Float16)b; return v.u;
}
__device__ __forceinline__ u16 f2h(float f){
  union { _Float16 h; u16 u; } v; v.h = (_Float16)f; return v.u;
}
__device__ __forceinline__ float h2ff(u16 u){
  union { u16 u2; _Float16 h; } v; v.u2 = u; return (float)v.h;
}
__device__ __forceinline__ float dot2(uint32 a, uint32 b, float c){
  union { uint32 u; h2 h; } x, y; x.u = a; y.u = b;
#if __has_builtin(__builtin_amdgcn_fdot2)
  return __builtin_amdgcn_fdot2(x.h, y.h, c, false);
#else
  c = fmaf((float)x.h[0], (float)y.h[0], c);
  return fmaf((float)x.h[1], (float)y.h[1], c);
#endif
}

struct KParams {
  const float *in, *W1, *b1, *W2, *b2, *W3, *Wih, *Whh, *bih, *bhh;
  float *out;          // [weighted B*99*128 | encoded B*99*256] f32
  const uint32 *Wgw;   // [64 p][1024 j]            w-part (reg-parked)
  const uint32 *Whp;   // [2 c][32 kb][1024 j][4 i] h-part (stream + LDS park)
  const uint32 *W1c;   // [2 c][64 kpb][128 s][4 i] W1 (stream)
};

// ---- pack weights to f16 pairs (runs once per launch; ~1.5MB, trivial) ----
__global__ void pack_kernel(const float* W1, const float* Wih, const float* Whh,
                            uint32* Wgw, uint32* Whp, uint32* W1c)
{
  int idx = blockIdx.x * 256 + threadIdx.x;
  if (idx < 64 * 1024) {                       // Wgw[p][j]
    int p = idx >> 10, j = idx & 1023;
    Wgw[idx] = pk2(Wih[(size_t)j * 128 + 2 * p],
                   Wih[(size_t)j * 128 + 2 * p + 1]);
  } else if (idx < 64 * 1024 + 2 * 32 * 1024 * 4) {
    int v = idx - 64 * 1024;                   // Whp[c][kb][j][i]
    int i = v & 3, j = (v >> 2) & 1023, kb = (v >> 12) & 31;
    int ph = kb * 4 + i;                       // h-pair 0..127
    Whp[v] = pk2(Whh[(size_t)j * 256 + 2 * ph],
                 Whh[(size_t)j * 256 + 2 * ph + 1]);
  } else {
    int w = idx - (64 * 1024 + 2 * 32 * 1024 * 4);
    if (w < 2 * 64 * 128 * 4) {                // W1c[c][kpb][s][i]
      int i = w & 3, s = (w >> 2) & 127, kpb = (w >> 9) & 63;
      int kp = kpb * 4 + i;                    // k-pair over [h(128)|c(128)]
      uint32 r = 0;
      if (s < TS) r = pk2(W1[(size_t)s * 512 + 2 * kp],
                          W1[(size_t)s * 512 + 2 * kp + 1]);
      W1c[w] = r;
    }
  }
}

// consume one h/w kb: 2 weight u4 (rows tid, tid+512) x 2 batch broadcasts
#define GCONS1(XB, W0, W1R, kb) do {                                   \
    u4 x0_ = *(const u4*)&XB[0][(kb) * 4];                             \
    u4 x1_ = *(const u4*)&XB[1][(kb) * 4];                             \
    _Pragma("unroll")                                                  \
    for (int ii_ = 0; ii_ < 4; ++ii_) {                                \
      a00 = dot2(W0[ii_], x0_[ii_], a00);                              \
      a01 = dot2(W1R[ii_], x0_[ii_], a01);                             \
      a10 = dot2(W0[ii_], x1_[ii_], a10);                              \
      a11 = dot2(W1R[ii_], x1_[ii_], a11);                             \
    } } while (0)

#define GCONS4(P0,P1,P2,P3,P4,P5,P6,P7, kb) do {                       \
    GCONS1(hcp, P0, P1, (kb));     GCONS1(hcp, P2, P3, (kb) + 1);      \
    GCONS1(hcp, P4, P5, (kb) + 2); GCONS1(hcp, P6, P7, (kb) + 3); } while (0)

#define LOADG(P0,P1,P2,P3,P4,P5,P6,P7, kb) do {                        \
    P0 = wh4[(kb) * 1024 + tid];       P1 = wh4[(kb) * 1024 + tid + 512];     \
    P2 = wh4[((kb)+1) * 1024 + tid];   P3 = wh4[((kb)+1) * 1024 + tid + 512]; \
    P4 = wh4[((kb)+2) * 1024 + tid];   P5 = wh4[((kb)+2) * 1024 + tid + 512]; \
    P6 = wh4[((kb)+3) * 1024 + tid];   P7 = wh4[((kb)+3) * 1024 + tid + 512]; \
  } while (0)

__global__ __launch_bounds__(512, 1) void enc_kernel(KParams p)
{
  // scratch: in[b][n][t] during prologue, then h-park (kbs 0..2, 48KB)
  __shared__ __align__(16) u16    scratch[2][128][102];
  __shared__ __align__(16) u16    z2s[2][128][102];   // f16 z2[b][n][s] (+b2)
  __shared__ __align__(16) uint32 hcp[2][256];        // f16 pairs: h|c
  __shared__ __align__(16) uint32 wp[2][64];          // f16 pairs: w[n]
  __shared__ __align__(16) float  z1part[2][4][128];
  __shared__ __align__(16) float  z1s[2][128];
  __shared__ float  epart[2][2][128];
  __shared__ float  gl[2][1024];
  __shared__ float  biasl[1024];
  __shared__ float  w3s[128], b1s[128];

  const int tid = threadIdx.x;
  const int blk = blockIdx.x;
  const int b0  = blk * 2;               // this block's two batches
  const int wc  = (blk >> 3) & 1;        // weight copy (alternates per group)

  float* outw = p.out;
  float* oute = p.out + (size_t)BB * TS * NN;

  // ---------------- prologue ----------------
  for (int b = 0; b < 2; ++b) {          // stage inputs f16, column layout
    const float* src = p.in + (size_t)(b0 + b) * TS * NN;
    for (int idx = tid; idx < TS * NN; idx += 512) {
      int t = idx >> 7, n = idx & 127;
      scratch[b][n][t] = f2h(src[idx]);
    }
  }
  if (tid < 128) {
    w3s[tid] = (tid < TS) ? p.W3[tid] : 0.f;
    b1s[tid] = (tid < TS) ? p.b1[tid] : 0.f;
  }
  hcp[tid >> 8][tid & 255] = 0;          // h = c = 0 at t=0  (512 covers all)
  biasl[tid]       = p.bih[tid]       + p.bhh[tid];
  biasl[tid + 512] = p.bih[tid + 512] + p.bhh[tid + 512];
  __syncthreads();
  {  // z2[b][n][s] = b2[s] + sum_t in[b][t][n] * W2[s][t]
    int n = tid & 127, b = (tid >> 7) & 1, hf = tid >> 8;
    int s0 = hf * 50, s1 = hf ? TS : 50;
    const u16* ir = scratch[b][n];
    for (int s = s0; s < s1; ++s) {
      float acc = p.b2[s];
      const float* w2r = p.W2 + s * TS;
      for (int tt = 0; tt + 1 < TS; tt += 2) {
        uint32 pr = *(const uint32*)&ir[tt];
        acc = fmaf(h2ff((u16)(pr & 0xFFFFu)), w2r[tt],     acc);
        acc = fmaf(h2ff((u16)(pr >> 16)),     w2r[tt + 1], acc);
      }
      acc = fmaf(h2ff(ir[98]), w2r[98], acc);
      z2s[b][n][s] = f2h(acc);
    }
  }
  __syncthreads();

  // ---- reg-park w-part (128 VGPR) + LDS-park h kbs 0..2 into scratch ----
  uint32 wg_w[128];
  #pragma unroll
  for (int i = 0; i < 64; ++i) wg_w[i] = p.Wgw[(size_t)i * 1024 + tid];
  #pragma unroll
  for (int i = 0; i < 64; ++i) wg_w[64 + i] = p.Wgw[(size_t)i * 1024 + tid + 512];

  u4* hp4 = (u4*)&scratch[0][0][0];      // [3 kb][1024 j] u4 = 48KB
  {
    const u4* src = (const u4*)p.Whp + (size_t)wc * 32768;
    #pragma unroll
    for (int r = 0; r < 6; ++r) hp4[r * 512 + tid] = src[r * 512 + tid];
  }
  __syncthreads();

  float creg = 0.f;                      // c for (lb, lu), f32 forever
  const int lu = tid & 255, lb = (tid >> 8) & 1;
  const int s127 = tid & 127, zq = tid >> 7;   // z1 ownership (4 k-quarters)

  const u4* wh4  = (const u4*)p.Whp + (size_t)wc * 32768;   // [32][1024] u4
  const u4* w1c4 = (const u4*)p.W1c + (size_t)wc * 8192;    // [64][128]  u4

  for (int t = 0; t < TS; ++t) {
    // block LICM of loop-invariant weight loads (R11/R12 hoist-then-spill)
    asm volatile("" : "+s"(wh4), "+s"(w1c4));

    float a00 = 0.f, a01 = 0.f, a10 = 0.f, a11 = 0.f;  // [batch][row-half]

    // ===== P1: z1 (W1 stream) + parked-h gate contribution =================
    {
      u4 w1b[16];
      #pragma unroll
      for (int i = 0; i < 16; ++i)
        w1b[i] = w1c4[(zq * 16 + i) * 128 + s127];
      #pragma unroll
      for (int kb = 0; kb < 3; ++kb) {   // LDS-parked h kbs (pairs 0..11)
        u4 w0 = hp4[kb * 1024 + tid];
        u4 w1r = hp4[kb * 1024 + tid + 512];
        GCONS1(hcp, w0, w1r, kb);
      }
      float za0 = 0.f, za1 = 0.f;
      #pragma unroll
      for (int i = 0; i < 16; ++i) {
        u4 x0 = *(const u4*)&hcp[0][(zq * 16 + i) * 4];
        u4 x1 = *(const u4*)&hcp[1][(zq * 16 + i) * 4];
        #pragma unroll
        for (int ii = 0; ii < 4; ++ii) {
          za0 = dot2(w1b[i][ii], x0[ii], za0);
          za1 = dot2(w1b[i][ii], x1[ii], za1);
        }
      }
      z1part[0][zq][s127] = za0;
      z1part[1][zq][s127] = za1;
    }
    __syncthreads();

    // ===== P2: z1 reduce ===================================================
    if (tid < 256) {
      int b = tid >> 7, s = tid & 127;
      z1s[b][s] = b1s[s] + ((z1part[b][0][s] + z1part[b][1][s])
                          + (z1part[b][2][s] + z1part[b][3][s]));
    }
    __syncthreads();

    // ===== P3: h-gates stream (kbs 3..31) + E phase, one barrier region ====
    {
      u4 A0,A1,A2,A3,A4,A5,A6,A7, B0,B1,B2,B3,B4,B5,B6,B7;
      LOADG(A0,A1,A2,A3,A4,A5,A6,A7, 3);
      LOADG(B0,B1,B2,B3,B4,B5,B6,B7, 7);
      {  // E: e[b][n] = sum_s w3[s] * tanh(z1[b][s] + z2[b][n][s])
        int n = tid & 127, b = (tid >> 7) & 1, hf = tid >> 8;
        int s0 = hf * 50, s1 = hf ? TS : 50;
        const u16* zr = z2s[b][n];
        float acce = 0.f;
        for (int s = s0; s < s1; ++s)
          acce = fmaf(w3s[s], ftanh(z1s[b][s] + h2ff(zr[s])), acce);
        epart[b][hf][n] = acce;
      }
      GCONS4(A0,A1,A2,A3,A4,A5,A6,A7, 3);
      LOADG(A0,A1,A2,A3,A4,A5,A6,A7, 11);
      GCONS4(B0,B1,B2,B3,B4,B5,B6,B7, 7);
      LOADG(B0,B1,B2,B3,B4,B5,B6,B7, 15);
      GCONS4(A0,A1,A2,A3,A4,A5,A6,A7, 11);
      LOADG(A0,A1,A2,A3,A4,A5,A6,A7, 19);
      GCONS4(B0,B1,B2,B3,B4,B5,B6,B7, 15);
      LOADG(B0,B1,B2,B3,B4,B5,B6,B7, 23);
      GCONS4(A0,A1,A2,A3,A4,A5,A6,A7, 19);
      LOADG(A0,A1,A2,A3,A4,A5,A6,A7, 27);
      GCONS4(B0,B1,B2,B3,B4,B5,B6,B7, 23);
      B0 = wh4[31 * 1024 + tid];
      B1 = wh4[31 * 1024 + tid + 512];
      GCONS4(A0,A1,A2,A3,A4,A5,A6,A7, 27);
      GCONS1(hcp, B0, B1, 31);
    }
    __syncthreads();

    // ===== P4: softmax + w = attn * x_t (waves 0-1) ========================
    if (tid < 128) {
      int b = tid >> 6, ln = tid & 63;
      float v0 = epart[b][0][ln]      + epart[b][1][ln];
      float v1 = epart[b][0][ln + 64] + epart[b][1][ln + 64];
      float m = fmaxf(v0, v1);
      for (int off = 32; off; off >>= 1) m = fmaxf(m, __shfl_xor(m, off));
      float e0 = __expf(v0 - m), e1 = __expf(v1 - m);
      float sm = e0 + e1;
      for (int off = 32; off; off >>= 1) sm += __shfl_xor(sm, off);
      float r = frcp(sm);
      const float* xr = p.in + ((size_t)(b0 + b) * TS + t) * NN;
      float w0 = e0 * r * xr[ln];
      float w1 = e1 * r * xr[ln + 64];
      float* orow = outw + ((size_t)(b0 + b) * TS + t) * NN;
      orow[ln]      = w0;                // f32 output
      orow[ln + 64] = w1;
      float w0n = __shfl_xor(w0, 1), w1n = __shfl_xor(w1, 1);
      if ((ln & 1) == 0) {               // pack adjacent-n pairs as f16x2
        wp[b][ln >> 1]        = pk2(w0, w0n);
        wp[b][32 + (ln >> 1)] = pk2(w1, w1n);
      }
    }
    __syncthreads();

    // ===== P5: w-gates from PARKED regs + gl write =========================
    #pragma unroll
    for (int kb = 0; kb < 16; ++kb) {
      u4 x0 = *(const u4*)&wp[0][kb * 4];
      u4 x1 = *(const u4*)&wp[1][kb * 4];
      #pragma unroll
      for (int i = 0; i < 4; ++i) {
        a00 = dot2(wg_w[kb * 4 + i],      x0[i], a00);
        a01 = dot2(wg_w[64 + kb * 4 + i], x0[i], a01);
        a10 = dot2(wg_w[kb * 4 + i],      x1[i], a10);
        a11 = dot2(wg_w[64 + kb * 4 + i], x1[i], a11);
      }
    }
    gl[0][tid]       = a00 + biasl[tid];
    gl[0][tid + 512] = a01 + biasl[tid + 512];
    gl[1][tid]       = a10 + biasl[tid];
    gl[1][tid + 512] = a11 + biasl[tid + 512];
    __syncthreads();

    // ===== P6: LSTM pointwise + h,c repack =================================
    {
      float iv = gl[lb][lu],       fv = gl[lb][256 + lu];
      float gv = gl[lb][512 + lu], ov = gl[lb][768 + lu];
      float cn = fsig(fv) * creg + fsig(iv) * ftanh(gv);
      float hn = fsig(ov) * ftanh(cn);
      creg = cn;
      oute[((size_t)(b0 + lb) * TS + t) * HH + lu] = hn;   // f32 output
      float hx = __shfl_xor(hn, 1);      // lu parity == lane parity
      float cx = __shfl_xor(cn, 1);
      if ((lu & 1) == 0) {
        hcp[lb][lu >> 1]         = pk2(hn, hx);
        hcp[lb][128 + (lu >> 1)] = pk2(cn, cx);
      }
    }
    __syncthreads();
  }
}

extern "C" void kernel_launch(void* const* d_in, const int* in_sizes, int n_in,
                              void* d_out, int out_size, void* d_ws, size_t ws_size,
                              hipStream_t stream)
{
  KParams p;
  p.in  = (const float*)d_in[0];
  p.W1  = (const float*)d_in[1];
  p.b1  = (const float*)d_in[2];
  p.W2  = (const float*)d_in[3];
  p.b2  = (const float*)d_in[4];
  p.W3  = (const float*)d_in[5];
  // d_in[6] = b3: softmax shift-invariant, unused
  p.Wih = (const float*)d_in[7];
  p.Whh = (const float*)d_in[8];
  p.bih = (const float*)d_in[9];
  p.bhh = (const float*)d_in[10];
  p.out = (float*)d_out;

  char* ws = (char*)d_ws;
  const size_t wgwBytes = 64ull * 1024 * 4;            // 262,144
  const size_t whpBytes = 2ull * 32 * 1024 * 4 * 4;    // 1,048,576
  const size_t w1cBytes = 2ull * 64 * 128 * 4 * 4;     // 262,144
  const size_t needBytes = wgwBytes + whpBytes + w1cBytes;  // 1,572,864
  if (ws_size < needBytes) return;  // fail loudly (poisoned output)

  uint32* Wgw = (uint32*)ws;
  uint32* Whp = (uint32*)(ws + wgwBytes);
  uint32* W1c = (uint32*)(ws + wgwBytes + whpBytes);
  p.Wgw = Wgw;
  p.Whp = Whp;
  p.W1c = W1c;

  // pack weights (fully covers all buffers; same-stream ordering guarantees
  // visibility; no flags -> no memset needed)
  const int packElems = 64 * 1024 + 2 * 32 * 1024 * 4 + 2 * 64 * 128 * 4;
  pack_kernel<<<dim3((packElems + 255) / 256), dim3(256), 0, stream>>>(
      p.W1, p.Wih, p.Whh, Wgw, Whp, W1c);

  enc_kernel<<<dim3(256), dim3(512), 0, stream>>>(p);
}